// Round 1
// baseline (2419.559 us; speedup 1.0000x reference)
//
#include <hip/hip_runtime.h>

// HWTV: ADMM TV solver, 124 independent 128x128 images, 20 iterations.
// One workgroup per image; whole iteration loop in-kernel (no cross-image
// coupling). 2D FFT solve done in LDS (float2, 128KB, dynamic-LDS opt-in).
// Persistent per-image state in d_ws: X, G1, Bh(=mu2*Uh+G21), Bv  ->
//   4 * 124 * 16384 * 4B = 31 MB of workspace.
// FFT: radix-2 DIF forward (bit-rev output) -> pointwise solve with
// bit-rev-indexed denom table -> radix-2 DIT inverse (bit-rev input).
// 1/N^2 folded into the pointwise solve.

#define NPIX   16384
#define NSIDE  128
#define NIMG   124
#define NT     1024
#define PXT    16          // pixels per thread
#define N_ITE  20
#define LAM_F  0.1f
#define RHO_F  1.05f
#define PI_F   3.14159265358979323846f

__device__ __forceinline__ void bfly_fwd(float2& A, float2& B, float wr, float wi) {
    float ar = A.x, ai = A.y, br = B.x, bi = B.y;
    A.x = ar + br; A.y = ai + bi;
    float tr = ar - br, ti = ai - bi;
    B.x = tr * wr - ti * wi;
    B.y = tr * wi + ti * wr;
}

__device__ __forceinline__ void bfly_inv(float2& A, float2& B, float wr, float wi) {
    // b * conj(w), then a+b / a-b
    float ar = A.x, ai = A.y, br = B.x, bi = B.y;
    float pr = br * wr + bi * wi;
    float pi = bi * wr - br * wi;
    A.x = ar + pr; A.y = ai + pi;
    B.x = ar - pr; B.y = ai - pi;
}

__global__ __launch_bounds__(NT) void hwtv_kernel(
    const float* __restrict__ Yg,
    const float* __restrict__ Wg,
    float* __restrict__ outg,
    float* __restrict__ wsg)
{
    extern __shared__ char smem[];
    float2* C  = (float2*)smem;                            // 16384 complex (128 KB)
    float2* TW = (float2*)(smem + (size_t)NPIX * 8);       // 64 twiddles W_128^k
    float*  D1 = (float*)(smem + (size_t)NPIX * 8 + 64*8); // 128: 4sin^2(pi*bitrev7(i)/128)

    const int tid = threadIdx.x;
    const size_t base  = (size_t)blockIdx.x * NPIX;
    const float* Y  = Yg + base;
    const float* Wt = Wg + base;
    float* out = outg + base;
    const size_t plane = (size_t)NIMG * NPIX;
    float* Xg  = wsg + base;
    float* G1g = wsg + plane     + base;
    float* Bhg = wsg + 2 * plane + base;
    float* Bvg = wsg + 3 * plane + base;

    // ---- one-time tables + Z0 = Y into LDS ----
    if (tid < 64) {
        float ang = -2.0f * PI_F * (float)tid / 128.0f;
        TW[tid] = make_float2(cosf(ang), sinf(ang));
    }
    if (tid < 128) {
        int br = (int)(__brev((unsigned)tid) >> 25);       // bitrev7
        float s = sinf(PI_F * (float)br / 128.0f);
        D1[tid] = 4.0f * s * s;
    }
    for (int k = 0; k < PXT; ++k) {
        int p = tid + k * NT;
        C[p] = make_float2(Y[p], 0.0f);
    }
    __syncthreads();

    float mu1 = 0.1f, mu2 = 0.1f;

    for (int it = 0; it < N_ITE; ++it) {
        const float mu2p   = mu2 * (1.0f / RHO_F);  // previous iteration's mu2
        const float inv_m2 = 1.0f / mu2;
        const float thr    = LAM_F * inv_m2;

        // ---- Phase A: shrink step; Bh = mu2*Uh + G21, Bv = mu2*Uv + G22 ----
        // Z (current) is in C[].x; G21 reconstructed as Bh_old - mu2p*DhZ.
        for (int k = 0; k < PXT; ++k) {
            int p    = tid + k * NT;
            int col  = p & (NSIDE - 1);
            int rowb = p & ~(NSIDE - 1);
            float z  = C[p].x;
            float zl = C[rowb | ((col + NSIDE - 1) & (NSIDE - 1))].x;
            float zu = C[(p + NPIX - NSIDE) & (NPIX - 1)].x;
            float dhz = z - zl;
            float dvz = z - zu;
            float g21 = 0.0f, g22 = 0.0f;
            if (it > 0) {
                g21 = Bhg[p] - mu2p * dhz;
                g22 = Bvg[p] - mu2p * dvz;
            }
            float ah = dhz - g21 * inv_m2;
            float av = dvz - g22 * inv_m2;
            float uh = copysignf(fmaxf(fabsf(ah) - thr, 0.0f), ah);
            float uv = copysignf(fmaxf(fabsf(av) - thr, 0.0f), av);
            Bhg[p] = fmaf(mu2, uh, g21);
            Bvg[p] = fmaf(mu2, uv, g22);
        }
        __syncthreads();

        // ---- Phase B: numerator = mu1*X + G1 + Dh^T Bh + Dv^T Bv -> C ----
        for (int k = 0; k < PXT; ++k) {
            int p    = tid + k * NT;
            int col  = p & (NSIDE - 1);
            int rowb = p & ~(NSIDE - 1);
            float x  = (it == 0) ? Y[p] : Xg[p];
            float g1 = (it == 0) ? 0.0f : G1g[p];
            float bh  = Bhg[p];
            float bhr = Bhg[rowb | ((col + 1) & (NSIDE - 1))];
            float bv  = Bvg[p];
            float bvd = Bvg[(p + NSIDE) & (NPIX - 1)];
            float num = fmaf(mu1, x, g1) + (bh - bhr) + (bv - bvd);
            C[p] = make_float2(num, 0.0f);
        }
        __syncthreads();

        // ---- forward FFT over rows (DIF, natural in -> bit-rev out) ----
        for (int s = 0; s < 7; ++s) {
            const int len = 64 >> s;
            for (int q = 0; q < 8; ++q) {
                int tau = tid + q * NT;            // 0..8191
                int t   = tau & 63;                // butterfly within row
                int org = (tau >> 6) << 7;         // row * 128
                int j   = t & (len - 1);
                int i0  = ((t ^ j) << 1) | j;
                float2 w = TW[j << s];
                float2 A = C[org + i0];
                float2 B = C[org + i0 + len];
                bfly_fwd(A, B, w.x, w.y);
                C[org + i0]       = A;
                C[org + i0 + len] = B;
            }
            __syncthreads();
        }
        // ---- forward FFT over cols (DIF) ----
        for (int s = 0; s < 7; ++s) {
            const int len = 64 >> s;
            for (int q = 0; q < 8; ++q) {
                int tau = tid + q * NT;
                int c   = tau & (NSIDE - 1);
                int t   = tau >> 7;                // 0..63
                int j   = t & (len - 1);
                int i0  = ((t ^ j) << 1) | j;
                int b0  = i0 * NSIDE + c;
                float2 w = TW[j << s];
                float2 A = C[b0];
                float2 B = C[b0 + len * NSIDE];
                bfly_fwd(A, B, w.x, w.y);
                C[b0]               = A;
                C[b0 + len * NSIDE] = B;
            }
            __syncthreads();
        }

        // ---- pointwise Fourier solve (bit-rev indexed), 1/N^2 folded in ----
        {
            const float sc = 1.0f / (float)NPIX;
            for (int k = 0; k < PXT; ++k) {
                int p = tid + k * NT;
                float den = mu1 + mu2 * (D1[p >> 7] + D1[p & (NSIDE - 1)]);
                float f = sc / den;
                float2 v = C[p];
                C[p] = make_float2(v.x * f, v.y * f);
            }
            __syncthreads();
        }

        // ---- inverse FFT over cols (DIT, bit-rev in -> natural out) ----
        for (int s = 0; s < 7; ++s) {
            const int len = 1 << s;
            for (int q = 0; q < 8; ++q) {
                int tau = tid + q * NT;
                int c   = tau & (NSIDE - 1);
                int t   = tau >> 7;
                int j   = t & (len - 1);
                int i0  = ((t ^ j) << 1) | j;
                int b0  = i0 * NSIDE + c;
                float2 w = TW[j << (6 - s)];
                float2 A = C[b0];
                float2 B = C[b0 + len * NSIDE];
                bfly_inv(A, B, w.x, w.y);
                C[b0]               = A;
                C[b0 + len * NSIDE] = B;
            }
            __syncthreads();
        }
        // ---- inverse FFT over rows (DIT) ----
        for (int s = 0; s < 7; ++s) {
            const int len = 1 << s;
            for (int q = 0; q < 8; ++q) {
                int tau = tid + q * NT;
                int t   = tau & 63;
                int org = (tau >> 6) << 7;
                int j   = t & (len - 1);
                int i0  = ((t ^ j) << 1) | j;
                float2 w = TW[j << (6 - s)];
                float2 A = C[org + i0];
                float2 B = C[org + i0 + len];
                bfly_inv(A, B, w.x, w.y);
                C[org + i0]       = A;
                C[org + i0 + len] = B;
            }
            __syncthreads();
        }

        // ---- Phase H: X/G1 update; Z stays in C[].x for next iteration ----
        for (int k = 0; k < PXT; ++k) {
            int p = tid + k * NT;
            float z  = C[p].x;
            float g1 = (it == 0) ? 0.0f : G1g[p];
            float w  = Wt[p];
            float x  = fmaf(w, Y[p], fmaf(mu1, z, -g1)) / (w + mu1);
            g1 = fmaf(mu1, x - z, g1);
            Xg[p]  = x;
            G1g[p] = g1;
            if (it == N_ITE - 1) out[p] = z;
        }
        __syncthreads();

        mu1 *= RHO_F;
        mu2 *= RHO_F;
    }
}

extern "C" void kernel_launch(void* const* d_in, const int* in_sizes, int n_in,
                              void* d_out, int out_size, void* d_ws, size_t ws_size,
                              hipStream_t stream) {
    (void)in_sizes; (void)n_in; (void)out_size; (void)ws_size;
    const float* Y   = (const float*)d_in[0];
    const float* inW = (const float*)d_in[1];
    float* out = (float*)d_out;
    float* ws  = (float*)d_ws;   // needs >= 31 MB

    const size_t smem_bytes = (size_t)NPIX * 8 + 64 * 8 + 128 * 4;  // 132096
    hipFuncSetAttribute((const void*)hwtv_kernel,
                        hipFuncAttributeMaxDynamicSharedMemorySize,
                        (int)smem_bytes);
    hipLaunchKernelGGL(hwtv_kernel, dim3(NIMG), dim3(NT), smem_bytes, stream,
                       Y, inW, out, ws);
}

// Round 2
// 1547.109 us; speedup vs baseline: 1.5639x; 1.5639x over previous
//
#include <hip/hip_runtime.h>

// HWTV: ADMM TV solver, 124 independent 128x128 images, 20 iterations.
// One workgroup per image; whole iteration loop in-kernel.
// Round 2: ALL cross-iteration state register-resident (a = mu1*X+G1, g1,
// bh = mu2*Uh+G21, bv = mu2*Uv+G22 -> 64 VGPRs/thread for 16 px). Neighbor
// exchange (bh right, bv down, z left/up) goes through the LDS C array in a
// fused 4-barrier prologue. Zero global workspace traffic; Y/inW re-read per
// iteration (L2-resident: 2 MB/XCD). d_ws unused.
// FFT: radix-2 DIF forward (bit-rev out) -> pointwise solve with bit-rev
// denom table -> radix-2 DIT inverse (bit-rev in). 1/N^2 folded into solve.

#define NPIX   16384
#define NSIDE  128
#define NIMG   124
#define NT     1024
#define PXT    16          // pixels per thread
#define N_ITE  20
#define LAM_F  0.1f
#define RHO_F  1.05f
#define PI_F   3.14159265358979323846f

__device__ __forceinline__ void bfly_fwd(float2& A, float2& B, float wr, float wi) {
    float ar = A.x, ai = A.y, br = B.x, bi = B.y;
    A.x = ar + br; A.y = ai + bi;
    float tr = ar - br, ti = ai - bi;
    B.x = tr * wr - ti * wi;
    B.y = tr * wi + ti * wr;
}

__device__ __forceinline__ void bfly_inv(float2& A, float2& B, float wr, float wi) {
    // b * conj(w), then a+b / a-b
    float ar = A.x, ai = A.y, br = B.x, bi = B.y;
    float pr = br * wr + bi * wi;
    float pi = bi * wr - br * wi;
    A.x = ar + pr; A.y = ai + pi;
    B.x = ar - pr; B.y = ai - pi;
}

__global__ __launch_bounds__(NT) void hwtv_kernel(
    const float* __restrict__ Yg,
    const float* __restrict__ Wg,
    float* __restrict__ outg)
{
    extern __shared__ char smem[];
    float2* C  = (float2*)smem;                            // 16384 complex (128 KB)
    float2* TW = (float2*)(smem + (size_t)NPIX * 8);       // 64 twiddles W_128^k
    float*  D1 = (float*)(smem + (size_t)NPIX * 8 + 64*8); // 128: 4sin^2(pi*bitrev7(i)/128)

    const int tid = threadIdx.x;
    const size_t base  = (size_t)blockIdx.x * NPIX;
    const float* Y  = Yg + base;
    const float* Wt = Wg + base;
    float* out = outg + base;

    // ---- one-time tables + Z0 = Y into LDS ----
    if (tid < 64) {
        float ang = -2.0f * PI_F * (float)tid / 128.0f;
        TW[tid] = make_float2(cosf(ang), sinf(ang));
    }
    if (tid < 128) {
        int br = (int)(__brev((unsigned)tid) >> 25);       // bitrev7
        float s = sinf(PI_F * (float)br / 128.0f);
        D1[tid] = 4.0f * s * s;
    }

    // persistent register state (per owned pixel p = tid + k*NT):
    //   a  = mu1*X + G1        (consumed in P3, produced in epilogue)
    //   g1 = G1
    //   bh = mu2*Uh + G21      (g21 reconstructed next iter: bh - mu2_prev*DhZ)
    //   bv = mu2*Uv + G22
    float a[PXT], g1[PXT], bh[PXT], bv[PXT];
    #pragma unroll
    for (int k = 0; k < PXT; ++k) {
        int p = tid + k * NT;
        float y = Y[p];
        C[p] = make_float2(y, 0.0f);     // Z0 = Y
        a[k]  = 0.1f * y;                // mu1*X0 + G1_0 = mu1*Y
        g1[k] = 0.0f;
        bh[k] = 0.0f;
        bv[k] = 0.0f;
    }
    __syncthreads();

    float mu1 = 0.1f, mu2 = 0.1f;

    for (int it = 0; it < N_ITE; ++it) {
        const float mu2p   = mu2 * (1.0f / RHO_F);  // previous iteration's mu2
        const float inv_m2 = 1.0f / mu2;
        const float thr    = LAM_F * inv_m2;

        // ---- P1: shrink; bh_new = mu2*Uh + G21, bv_new = mu2*Uv + G22 ----
        // Z (current) in C[].x; G21 = bh_old - mu2_prev*DhZ (DhZ of current Z).
        #pragma unroll
        for (int k = 0; k < PXT; ++k) {
            int p    = tid + k * NT;
            int col  = p & (NSIDE - 1);
            int rowb = p & ~(NSIDE - 1);
            float z  = C[p].x;
            float zl = C[rowb | ((col + NSIDE - 1) & (NSIDE - 1))].x;
            float zu = C[(p + NPIX - NSIDE) & (NPIX - 1)].x;
            float dhz = z - zl;
            float dvz = z - zu;
            float g21 = (it == 0) ? 0.0f : fmaf(-mu2p, dhz, bh[k]);
            float g22 = (it == 0) ? 0.0f : fmaf(-mu2p, dvz, bv[k]);
            float ah = dhz - g21 * inv_m2;
            float av = dvz - g22 * inv_m2;
            float uh = copysignf(fmaxf(fabsf(ah) - thr, 0.0f), ah);
            float uv = copysignf(fmaxf(fabsf(av) - thr, 0.0f), av);
            bh[k] = fmaf(mu2, uh, g21);
            bv[k] = fmaf(mu2, uv, g22);
        }
        __syncthreads();          // all Z reads done before overwriting C

        // ---- P2: stage (bh, bv) in C for neighbor exchange ----
        #pragma unroll
        for (int k = 0; k < PXT; ++k) {
            int p = tid + k * NT;
            C[p] = make_float2(bh[k], bv[k]);
        }
        __syncthreads();

        // ---- P3: numerator = a + Dh^T bh + Dv^T bv ----
        float numv[PXT];
        #pragma unroll
        for (int k = 0; k < PXT; ++k) {
            int p    = tid + k * NT;
            int col  = p & (NSIDE - 1);
            int rowb = p & ~(NSIDE - 1);
            float bhr = C[rowb | ((col + 1) & (NSIDE - 1))].x;
            float bvd = C[(p + NSIDE) & (NPIX - 1)].y;
            numv[k] = a[k] + (bh[k] - bhr) + (bv[k] - bvd);
        }
        __syncthreads();          // all neighbor reads done before overwrite

        // ---- P4: C <- numerator (real) ----
        #pragma unroll
        for (int k = 0; k < PXT; ++k) {
            int p = tid + k * NT;
            C[p] = make_float2(numv[k], 0.0f);
        }
        __syncthreads();

        // ---- forward FFT over rows (DIF, natural in -> bit-rev out) ----
        for (int s = 0; s < 7; ++s) {
            const int len = 64 >> s;
            #pragma unroll
            for (int q = 0; q < 8; ++q) {
                int tau = tid + q * NT;            // 0..8191
                int t   = tau & 63;                // butterfly within row
                int org = (tau >> 6) << 7;         // row * 128
                int j   = t & (len - 1);
                int i0  = ((t ^ j) << 1) | j;
                float2 w = TW[j << s];
                float2 A = C[org + i0];
                float2 B = C[org + i0 + len];
                bfly_fwd(A, B, w.x, w.y);
                C[org + i0]       = A;
                C[org + i0 + len] = B;
            }
            __syncthreads();
        }
        // ---- forward FFT over cols (DIF) ----
        for (int s = 0; s < 7; ++s) {
            const int len = 64 >> s;
            #pragma unroll
            for (int q = 0; q < 8; ++q) {
                int tau = tid + q * NT;
                int c   = tau & (NSIDE - 1);
                int t   = tau >> 7;                // 0..63
                int j   = t & (len - 1);
                int i0  = ((t ^ j) << 1) | j;
                int b0  = i0 * NSIDE + c;
                float2 w = TW[j << s];
                float2 A = C[b0];
                float2 B = C[b0 + len * NSIDE];
                bfly_fwd(A, B, w.x, w.y);
                C[b0]               = A;
                C[b0 + len * NSIDE] = B;
            }
            __syncthreads();
        }

        // ---- pointwise Fourier solve (bit-rev indexed), 1/N^2 folded in ----
        {
            const float sc = 1.0f / (float)NPIX;
            #pragma unroll
            for (int k = 0; k < PXT; ++k) {
                int p = tid + k * NT;
                float den = mu1 + mu2 * (D1[p >> 7] + D1[p & (NSIDE - 1)]);
                float f = sc / den;
                float2 v = C[p];
                C[p] = make_float2(v.x * f, v.y * f);
            }
            __syncthreads();
        }

        // ---- inverse FFT over cols (DIT, bit-rev in -> natural out) ----
        for (int s = 0; s < 7; ++s) {
            const int len = 1 << s;
            #pragma unroll
            for (int q = 0; q < 8; ++q) {
                int tau = tid + q * NT;
                int c   = tau & (NSIDE - 1);
                int t   = tau >> 7;
                int j   = t & (len - 1);
                int i0  = ((t ^ j) << 1) | j;
                int b0  = i0 * NSIDE + c;
                float2 w = TW[j << (6 - s)];
                float2 A = C[b0];
                float2 B = C[b0 + len * NSIDE];
                bfly_inv(A, B, w.x, w.y);
                C[b0]               = A;
                C[b0 + len * NSIDE] = B;
            }
            __syncthreads();
        }
        // ---- inverse FFT over rows (DIT) ----
        for (int s = 0; s < 7; ++s) {
            const int len = 1 << s;
            #pragma unroll
            for (int q = 0; q < 8; ++q) {
                int tau = tid + q * NT;
                int t   = tau & 63;
                int org = (tau >> 6) << 7;
                int j   = t & (len - 1);
                int i0  = ((t ^ j) << 1) | j;
                float2 w = TW[j << (6 - s)];
                float2 A = C[org + i0];
                float2 B = C[org + i0 + len];
                bfly_inv(A, B, w.x, w.y);
                C[org + i0]       = A;
                C[org + i0 + len] = B;
            }
            __syncthreads();
        }

        // ---- Epilogue: X/G1/a update in registers; Z stays in C[].x ----
        const float mu1n = mu1 * RHO_F;
        #pragma unroll
        for (int k = 0; k < PXT; ++k) {
            int p = tid + k * NT;
            float z  = C[p].x;
            float y  = Y[p];
            float w  = Wt[p];
            float x  = fmaf(w, y, fmaf(mu1, z, -g1[k])) *
                       __builtin_amdgcn_rcpf(w + mu1);
            g1[k] = fmaf(mu1, x - z, g1[k]);
            a[k]  = fmaf(mu1n, x, g1[k]);
            if (it == N_ITE - 1) out[p] = z;
        }
        // no barrier needed: next P1 only reads C (covered by FFT's last
        // barrier); P2's writes are behind P1's barrier.

        mu1 *= RHO_F;
        mu2 *= RHO_F;
    }
}

extern "C" void kernel_launch(void* const* d_in, const int* in_sizes, int n_in,
                              void* d_out, int out_size, void* d_ws, size_t ws_size,
                              hipStream_t stream) {
    (void)in_sizes; (void)n_in; (void)out_size; (void)d_ws; (void)ws_size;
    const float* Y   = (const float*)d_in[0];
    const float* inW = (const float*)d_in[1];
    float* out = (float*)d_out;

    const size_t smem_bytes = (size_t)NPIX * 8 + 64 * 8 + 128 * 4;  // 132096
    hipFuncSetAttribute((const void*)hwtv_kernel,
                        hipFuncAttributeMaxDynamicSharedMemorySize,
                        (int)smem_bytes);
    hipLaunchKernelGGL(hwtv_kernel, dim3(NIMG), dim3(NT), smem_bytes, stream,
                       Y, inW, out);
}

// Round 3
// 1225.247 us; speedup vs baseline: 1.9748x; 1.2627x over previous
//
#include <hip/hip_runtime.h>

// HWTV: ADMM TV solver, 124 independent 128x128 images, 20 iterations.
// One workgroup per image; whole iteration loop in-kernel.
// Round 3: fix R2's register spill. R2 kept 64 persistent floats/thread but
// the compiler capped at 64 VGPR (targeting 8 waves/EU that LDS=128KB makes
// impossible) and spilled everything to scratch (~550 MB HBM traffic).
// __launch_bounds__(1024, 4) matches the real occupancy (1 block/CU) ->
// 128 VGPR cap. FFT butterfly loops unrolled x4 to bound transient pressure.
// State: a = mu1*X+G1, g1, bh = mu2*Uh+G21, bv = mu2*Uv+G22 in registers.
// FFT: radix-2 DIF forward (bit-rev out) -> pointwise solve with bit-rev
// denom table -> radix-2 DIT inverse (bit-rev in). 1/N^2 folded into solve.

#define NPIX   16384
#define NSIDE  128
#define NIMG   124
#define NT     1024
#define PXT    16          // pixels per thread
#define N_ITE  20
#define LAM_F  0.1f
#define RHO_F  1.05f
#define PI_F   3.14159265358979323846f

__device__ __forceinline__ void bfly_fwd(float2& A, float2& B, float wr, float wi) {
    float ar = A.x, ai = A.y, br = B.x, bi = B.y;
    A.x = ar + br; A.y = ai + bi;
    float tr = ar - br, ti = ai - bi;
    B.x = tr * wr - ti * wi;
    B.y = tr * wi + ti * wr;
}

__device__ __forceinline__ void bfly_inv(float2& A, float2& B, float wr, float wi) {
    // b * conj(w), then a+b / a-b
    float ar = A.x, ai = A.y, br = B.x, bi = B.y;
    float pr = br * wr + bi * wi;
    float pi = bi * wr - br * wi;
    A.x = ar + pr; A.y = ai + pi;
    B.x = ar - pr; B.y = ai - pi;
}

__global__ __launch_bounds__(NT, 4) void hwtv_kernel(
    const float* __restrict__ Yg,
    const float* __restrict__ Wg,
    float* __restrict__ outg)
{
    extern __shared__ char smem[];
    float2* C  = (float2*)smem;                            // 16384 complex (128 KB)
    float2* TW = (float2*)(smem + (size_t)NPIX * 8);       // 64 twiddles W_128^k
    float*  D1 = (float*)(smem + (size_t)NPIX * 8 + 64*8); // 128: 4sin^2(pi*bitrev7(i)/128)

    const int tid = threadIdx.x;
    const size_t base  = (size_t)blockIdx.x * NPIX;
    const float* Y  = Yg + base;
    const float* Wt = Wg + base;
    float* out = outg + base;

    // ---- one-time tables + Z0 = Y into LDS ----
    if (tid < 64) {
        float ang = -2.0f * PI_F * (float)tid / 128.0f;
        TW[tid] = make_float2(cosf(ang), sinf(ang));
    }
    if (tid < 128) {
        int br = (int)(__brev((unsigned)tid) >> 25);       // bitrev7
        float s = sinf(PI_F * (float)br / 128.0f);
        D1[tid] = 4.0f * s * s;
    }

    // persistent register state (per owned pixel p = tid + k*NT):
    //   a  = mu1*X + G1        (consumed in P3, produced in epilogue)
    //   g1 = G1
    //   bh = mu2*Uh + G21      (g21 reconstructed next iter: bh - mu2_prev*DhZ)
    //   bv = mu2*Uv + G22
    float a[PXT], g1[PXT], bh[PXT], bv[PXT];
    #pragma unroll
    for (int k = 0; k < PXT; ++k) {
        int p = tid + k * NT;
        float y = Y[p];
        C[p] = make_float2(y, 0.0f);     // Z0 = Y
        a[k]  = 0.1f * y;                // mu1*X0 + G1_0 = mu1*Y
        g1[k] = 0.0f;
        bh[k] = 0.0f;
        bv[k] = 0.0f;
    }
    __syncthreads();

    float mu1 = 0.1f, mu2 = 0.1f;

    for (int it = 0; it < N_ITE; ++it) {
        const float mu2p   = mu2 * (1.0f / RHO_F);  // previous iteration's mu2
        const float inv_m2 = 1.0f / mu2;
        const float thr    = LAM_F * inv_m2;

        // ---- P1: shrink; bh_new = mu2*Uh + G21, bv_new = mu2*Uv + G22 ----
        // Z (current) in C[].x; G21 = bh_old - mu2_prev*DhZ (DhZ of current Z).
        #pragma unroll 4
        for (int k = 0; k < PXT; ++k) {
            int p    = tid + k * NT;
            int col  = p & (NSIDE - 1);
            int rowb = p & ~(NSIDE - 1);
            float z  = C[p].x;
            float zl = C[rowb | ((col + NSIDE - 1) & (NSIDE - 1))].x;
            float zu = C[(p + NPIX - NSIDE) & (NPIX - 1)].x;
            float dhz = z - zl;
            float dvz = z - zu;
            float g21 = (it == 0) ? 0.0f : fmaf(-mu2p, dhz, bh[k]);
            float g22 = (it == 0) ? 0.0f : fmaf(-mu2p, dvz, bv[k]);
            float ah = dhz - g21 * inv_m2;
            float av = dvz - g22 * inv_m2;
            float uh = copysignf(fmaxf(fabsf(ah) - thr, 0.0f), ah);
            float uv = copysignf(fmaxf(fabsf(av) - thr, 0.0f), av);
            bh[k] = fmaf(mu2, uh, g21);
            bv[k] = fmaf(mu2, uv, g22);
        }
        __syncthreads();          // all Z reads done before overwriting C

        // ---- P2: stage (bh, bv) in C for neighbor exchange ----
        #pragma unroll 4
        for (int k = 0; k < PXT; ++k) {
            int p = tid + k * NT;
            C[p] = make_float2(bh[k], bv[k]);
        }
        __syncthreads();

        // ---- P3: numerator = a + Dh^T bh + Dv^T bv ----
        float numv[PXT];
        #pragma unroll 4
        for (int k = 0; k < PXT; ++k) {
            int p    = tid + k * NT;
            int col  = p & (NSIDE - 1);
            int rowb = p & ~(NSIDE - 1);
            float bhr = C[rowb | ((col + 1) & (NSIDE - 1))].x;
            float bvd = C[(p + NSIDE) & (NPIX - 1)].y;
            numv[k] = a[k] + (bh[k] - bhr) + (bv[k] - bvd);
        }
        __syncthreads();          // all neighbor reads done before overwrite

        // ---- P4: C <- numerator (real) ----
        #pragma unroll 4
        for (int k = 0; k < PXT; ++k) {
            int p = tid + k * NT;
            C[p] = make_float2(numv[k], 0.0f);
        }
        __syncthreads();

        // ---- forward FFT over rows (DIF, natural in -> bit-rev out) ----
        for (int s = 0; s < 7; ++s) {
            const int len = 64 >> s;
            #pragma unroll 4
            for (int q = 0; q < 8; ++q) {
                int tau = tid + q * NT;            // 0..8191
                int t   = tau & 63;                // butterfly within row
                int org = (tau >> 6) << 7;         // row * 128
                int j   = t & (len - 1);
                int i0  = ((t ^ j) << 1) | j;
                float2 w = TW[j << s];
                float2 A = C[org + i0];
                float2 B = C[org + i0 + len];
                bfly_fwd(A, B, w.x, w.y);
                C[org + i0]       = A;
                C[org + i0 + len] = B;
            }
            __syncthreads();
        }
        // ---- forward FFT over cols (DIF) ----
        for (int s = 0; s < 7; ++s) {
            const int len = 64 >> s;
            #pragma unroll 4
            for (int q = 0; q < 8; ++q) {
                int tau = tid + q * NT;
                int c   = tau & (NSIDE - 1);
                int t   = tau >> 7;                // 0..63
                int j   = t & (len - 1);
                int i0  = ((t ^ j) << 1) | j;
                int b0  = i0 * NSIDE + c;
                float2 w = TW[j << s];
                float2 A = C[b0];
                float2 B = C[b0 + len * NSIDE];
                bfly_fwd(A, B, w.x, w.y);
                C[b0]               = A;
                C[b0 + len * NSIDE] = B;
            }
            __syncthreads();
        }

        // ---- pointwise Fourier solve (bit-rev indexed), 1/N^2 folded in ----
        {
            const float sc = 1.0f / (float)NPIX;
            #pragma unroll 4
            for (int k = 0; k < PXT; ++k) {
                int p = tid + k * NT;
                float den = mu1 + mu2 * (D1[p >> 7] + D1[p & (NSIDE - 1)]);
                float f = sc / den;
                float2 v = C[p];
                C[p] = make_float2(v.x * f, v.y * f);
            }
            __syncthreads();
        }

        // ---- inverse FFT over cols (DIT, bit-rev in -> natural out) ----
        for (int s = 0; s < 7; ++s) {
            const int len = 1 << s;
            #pragma unroll 4
            for (int q = 0; q < 8; ++q) {
                int tau = tid + q * NT;
                int c   = tau & (NSIDE - 1);
                int t   = tau >> 7;
                int j   = t & (len - 1);
                int i0  = ((t ^ j) << 1) | j;
                int b0  = i0 * NSIDE + c;
                float2 w = TW[j << (6 - s)];
                float2 A = C[b0];
                float2 B = C[b0 + len * NSIDE];
                bfly_inv(A, B, w.x, w.y);
                C[b0]               = A;
                C[b0 + len * NSIDE] = B;
            }
            __syncthreads();
        }
        // ---- inverse FFT over rows (DIT) ----
        for (int s = 0; s < 7; ++s) {
            const int len = 1 << s;
            #pragma unroll 4
            for (int q = 0; q < 8; ++q) {
                int tau = tid + q * NT;
                int t   = tau & 63;
                int org = (tau >> 6) << 7;
                int j   = t & (len - 1);
                int i0  = ((t ^ j) << 1) | j;
                float2 w = TW[j << (6 - s)];
                float2 A = C[org + i0];
                float2 B = C[org + i0 + len];
                bfly_inv(A, B, w.x, w.y);
                C[org + i0]       = A;
                C[org + i0 + len] = B;
            }
            __syncthreads();
        }

        // ---- Epilogue: X/G1/a update in registers; Z stays in C[].x ----
        const float mu1n = mu1 * RHO_F;
        #pragma unroll 4
        for (int k = 0; k < PXT; ++k) {
            int p = tid + k * NT;
            float z  = C[p].x;
            float y  = Y[p];
            float w  = Wt[p];
            float x  = fmaf(w, y, fmaf(mu1, z, -g1[k])) *
                       __builtin_amdgcn_rcpf(w + mu1);
            g1[k] = fmaf(mu1, x - z, g1[k]);
            a[k]  = fmaf(mu1n, x, g1[k]);
            if (it == N_ITE - 1) out[p] = z;
        }
        // no barrier needed: next P1 only reads C (covered by FFT's last
        // barrier); P2's writes are behind P1's barrier.

        mu1 *= RHO_F;
        mu2 *= RHO_F;
    }
}

extern "C" void kernel_launch(void* const* d_in, const int* in_sizes, int n_in,
                              void* d_out, int out_size, void* d_ws, size_t ws_size,
                              hipStream_t stream) {
    (void)in_sizes; (void)n_in; (void)out_size; (void)d_ws; (void)ws_size;
    const float* Y   = (const float*)d_in[0];
    const float* inW = (const float*)d_in[1];
    float* out = (float*)d_out;

    const size_t smem_bytes = (size_t)NPIX * 8 + 64 * 8 + 128 * 4;  // 132096
    hipFuncSetAttribute((const void*)hwtv_kernel,
                        hipFuncAttributeMaxDynamicSharedMemorySize,
                        (int)smem_bytes);
    hipLaunchKernelGGL(hwtv_kernel, dim3(NIMG), dim3(NT), smem_bytes, stream,
                       Y, inW, out);
}